// Round 22
// baseline (76.938 us; speedup 1.0000x reference)
//
#include <hip/hip_runtime.h>

typedef __attribute__((ext_vector_type(8))) short short8;
typedef __attribute__((ext_vector_type(4))) short short4v;
typedef __attribute__((ext_vector_type(4))) float f32x4;

#define MFMA16(A, B, C) __builtin_amdgcn_mfma_f32_16x16x32_bf16(A, B, C, 0, 0, 0)

__device__ __forceinline__ short f2bf(float f) {
    union { float f; unsigned u; } v;
    v.f = f;
    unsigned r = (v.u + 0x7FFFu + ((v.u >> 16) & 1u)) >> 16;
    return (short)r;
}

__device__ __forceinline__ float bf2f(short u) {
    union { unsigned u; float f; } v;
    v.u = ((unsigned)(unsigned short)u) << 16;
    return v.f;
}

// 8x fp32 -> bf16x8 via v_cvt_pk_bf16_f32 (RNE, 1 op per pair).
__device__ __forceinline__ short8 cvt8(f32x4 a, f32x4 b) {
    unsigned u0, u1, u2, u3;
    asm("v_cvt_pk_bf16_f32 %0, %1, %2" : "=v"(u0) : "v"(a[0]), "v"(a[1]));
    asm("v_cvt_pk_bf16_f32 %0, %1, %2" : "=v"(u1) : "v"(a[2]), "v"(a[3]));
    asm("v_cvt_pk_bf16_f32 %0, %1, %2" : "=v"(u2) : "v"(b[0]), "v"(b[1]));
    asm("v_cvt_pk_bf16_f32 %0, %1, %2" : "=v"(u3) : "v"(b[2]), "v"(b[3]));
    union { unsigned u[4]; short8 s; } r;
    r.u[0] = u0; r.u[1] = u1; r.u[2] = u2; r.u[3] = u3;
    return r.s;
}

// 4x fp32 -> bf16x4 packed 8B store (for P strips).
__device__ __forceinline__ void cvtpk_store4(short* dst, float p0, float p1,
                                             float p2, float p3) {
    unsigned w01, w23;
    asm("v_cvt_pk_bf16_f32 %0, %1, %2" : "=v"(w01) : "v"(p0), "v"(p1));
    asm("v_cvt_pk_bf16_f32 %0, %1, %2" : "=v"(w23) : "v"(p2), "v"(p3));
    union { unsigned u[2]; short4v s; } r;
    r.u[0] = w01; r.u[1] = w23;
    *(short4v*)dst = r.s;
}

// ---------------------------------------------------------------------------
// Fused QKV GEMM (r21-proven), 128x128 tile, BK=64, reg-staged dbuf. Both
// panels fp32, converted to bf16 AT WRITE TIME (loads stay outstanding under
// MFMA). Grid (64, 12); z = e0>>9 block-uniform: 0->q, 1->k, 2->v^T.
// ---------------------------------------------------------------------------
__global__ __launch_bounds__(256) void qkv128(
    const float* __restrict__ X, const float* __restrict__ wq,
    const float* __restrict__ wk, const float* __restrict__ wv,
    const float* __restrict__ bq, const float* __restrict__ bk,
    const float* __restrict__ bv, short* __restrict__ qo,
    short* __restrict__ ko, short* __restrict__ vto) {
    __shared__ short As[128 * 72];
    __shared__ short Bs[128 * 72];
    const int tid = threadIdx.x, lane = tid & 63, wid = tid >> 6;
    const int c = lane & 15, g = lane >> 4;
    const int wr = (wid >> 1) * 64, wc = (wid & 1) * 64;
    const int m0 = blockIdx.x * 128, e0 = blockIdx.y * 128;
    const int z = e0 >> 9;
    const float* Wf = (z == 0) ? wq : (z == 1) ? wk : wv;  // block-uniform
    const int er0 = e0 & 511;

    const f32x4 Z = {0.f, 0.f, 0.f, 0.f};
    f32x4 acc[4][4];
#pragma unroll
    for (int i = 0; i < 4; ++i)
#pragma unroll
        for (int j = 0; j < 4; ++j) acc[i][j] = Z;

    // fp32 staging registers (converted at write time)
    f32x4 pa0[4], pa1[4], pb0[4], pb1[4];
#pragma unroll
    for (int p = 0; p < 4; ++p) {
        int u = p * 256 + tid;
        int row = u >> 3, c8 = u & 7;
        const float* xs = &X[(size_t)(m0 + row) * 512 + c8 * 8];
        const float* ws = &Wf[(size_t)(er0 + row) * 512 + c8 * 8];
        pa0[p] = *(const f32x4*)xs;  pa1[p] = *(const f32x4*)(xs + 4);
        pb0[p] = *(const f32x4*)ws;  pb1[p] = *(const f32x4*)(ws + 4);
    }
    for (int it = 0; it < 8; ++it) {
        __syncthreads();
#pragma unroll
        for (int p = 0; p < 4; ++p) {
            int u = p * 256 + tid;
            int row = u >> 3, c8 = u & 7;
            *(short8*)&As[row * 72 + c8 * 8] = cvt8(pa0[p], pa1[p]);
            *(short8*)&Bs[row * 72 + c8 * 8] = cvt8(pb0[p], pb1[p]);
        }
        if (it < 7) {
            int k0 = (it + 1) * 64;
#pragma unroll
            for (int p = 0; p < 4; ++p) {
                int u = p * 256 + tid;
                int row = u >> 3, c8 = u & 7;
                const float* xs = &X[(size_t)(m0 + row) * 512 + k0 + c8 * 8];
                const float* ws = &Wf[(size_t)(er0 + row) * 512 + k0 + c8 * 8];
                pa0[p] = *(const f32x4*)xs;  pa1[p] = *(const f32x4*)(xs + 4);
                pb0[p] = *(const f32x4*)ws;  pb1[p] = *(const f32x4*)(ws + 4);
            }
        }
        __syncthreads();
#pragma unroll
        for (int ks = 0; ks < 2; ++ks) {
            short8 af[4], bf[4];
#pragma unroll
            for (int mt = 0; mt < 4; ++mt)
                af[mt] = *(const short8*)&As[(wr + mt * 16 + c) * 72 + ks * 32 + g * 8];
#pragma unroll
            for (int nt = 0; nt < 4; ++nt)
                bf[nt] = *(const short8*)&Bs[(wc + nt * 16 + c) * 72 + ks * 32 + g * 8];
#pragma unroll
            for (int mt = 0; mt < 4; ++mt)
#pragma unroll
                for (int nt = 0; nt < 4; ++nt)
                    acc[mt][nt] = MFMA16(af[mt], bf[nt], acc[mt][nt]);
        }
    }

    // epilogue: route by z (block-uniform)
    const float* bp = (z == 0) ? bq : (z == 1) ? bk : bv;
    if (z < 2) {
        short* out = (z == 0) ? qo : ko;
#pragma unroll
        for (int nt = 0; nt < 4; ++nt) {
            int eh = er0 + wc + nt * 16 + c;
            float bsv = bp[eh];
            int h = eh >> 6, d = eh & 63;
#pragma unroll
            for (int mt = 0; mt < 4; ++mt)
#pragma unroll
                for (int r = 0; r < 4; ++r) {
                    int m = m0 + wr + mt * 16 + g * 4 + r;
                    int bb = m >> 9, n = m & 511;
                    out[(((size_t)bb * 8 + h) * 512 + n) * 64 + d] =
                        f2bf(acc[mt][nt][r] + bsv);
                }
        }
    } else {
#pragma unroll
        for (int nt = 0; nt < 4; ++nt) {
            int eh = er0 + wc + nt * 16 + c;
            float bsv = bp[eh];
            int h = eh >> 6, d = eh & 63;
#pragma unroll
            for (int mt = 0; mt < 4; ++mt) {
                int m = m0 + wr + mt * 16 + g * 4;
                int bb = m >> 9, n = m & 511;  // 4 consecutive n
                short4v w;
#pragma unroll
                for (int r = 0; r < 4; ++r) w[r] = f2bf(acc[mt][nt][r] + bsv);
                *(short4v*)&vto[(((size_t)bb * 8 + h) * 64 + d) * 512 + n] = w;
            }
        }
    }
}

// ---------------------------------------------------------------------------
// Output projection (r21-proven), 128x128 tile, reg-staged; wo fp32 held in
// registers, converted at write time. Grid (64, 4).
// ---------------------------------------------------------------------------
__global__ __launch_bounds__(256) void out128(const short* __restrict__ A,
                                              const float* __restrict__ Wf,
                                              const float* __restrict__ bo,
                                              float* __restrict__ out) {
    __shared__ short As[128 * 72];
    __shared__ short Bs[128 * 72];
    const int tid = threadIdx.x, lane = tid & 63, wid = tid >> 6;
    const int c = lane & 15, g = lane >> 4;
    const int wr = (wid >> 1) * 64, wc = (wid & 1) * 64;
    const int m0 = blockIdx.x * 128, e0 = blockIdx.y * 128;

    const f32x4 Z = {0.f, 0.f, 0.f, 0.f};
    f32x4 acc[4][4];
#pragma unroll
    for (int i = 0; i < 4; ++i)
#pragma unroll
        for (int j = 0; j < 4; ++j) acc[i][j] = Z;

    short8 pa[4];
    f32x4 pb0[4], pb1[4];
#pragma unroll
    for (int p = 0; p < 4; ++p) {
        int u = p * 256 + tid;
        int row = u >> 3, c8 = u & 7;
        pa[p] = *(const short8*)&A[(size_t)(m0 + row) * 512 + c8 * 8];
        const float* ws = &Wf[(size_t)(e0 + row) * 512 + c8 * 8];
        pb0[p] = *(const f32x4*)ws;  pb1[p] = *(const f32x4*)(ws + 4);
    }
    for (int it = 0; it < 8; ++it) {
        __syncthreads();
#pragma unroll
        for (int p = 0; p < 4; ++p) {
            int u = p * 256 + tid;
            int row = u >> 3, c8 = u & 7;
            *(short8*)&As[row * 72 + c8 * 8] = pa[p];
            *(short8*)&Bs[row * 72 + c8 * 8] = cvt8(pb0[p], pb1[p]);
        }
        if (it < 7) {
            int k0 = (it + 1) * 64;
#pragma unroll
            for (int p = 0; p < 4; ++p) {
                int u = p * 256 + tid;
                int row = u >> 3, c8 = u & 7;
                pa[p] = *(const short8*)&A[(size_t)(m0 + row) * 512 + k0 + c8 * 8];
                const float* ws = &Wf[(size_t)(e0 + row) * 512 + k0 + c8 * 8];
                pb0[p] = *(const f32x4*)ws;  pb1[p] = *(const f32x4*)(ws + 4);
            }
        }
        __syncthreads();
#pragma unroll
        for (int ks = 0; ks < 2; ++ks) {
            short8 af[4], bf[4];
#pragma unroll
            for (int mt = 0; mt < 4; ++mt)
                af[mt] = *(const short8*)&As[(wr + mt * 16 + c) * 72 + ks * 32 + g * 8];
#pragma unroll
            for (int nt = 0; nt < 4; ++nt)
                bf[nt] = *(const short8*)&Bs[(wc + nt * 16 + c) * 72 + ks * 32 + g * 8];
#pragma unroll
            for (int mt = 0; mt < 4; ++mt)
#pragma unroll
                for (int nt = 0; nt < 4; ++nt)
                    acc[mt][nt] = MFMA16(af[mt], bf[nt], acc[mt][nt]);
        }
    }

#pragma unroll
    for (int nt = 0; nt < 4; ++nt) {
        int e = e0 + wc + nt * 16 + c;
        float bsv = bo[e];
#pragma unroll
        for (int mt = 0; mt < 4; ++mt)
#pragma unroll
            for (int r = 0; r < 4; ++r) {
                int m = m0 + wr + mt * 16 + g * 4 + r;
                out[(size_t)m * 512 + e] = acc[mt][nt][r] + bsv;
            }
    }
}

// ---------------------------------------------------------------------------
// MFMA flash attention, SINGLE-BUFFERED block-shared K/V LDS staging:
// LDS 55.3KB -> 36.9KB doubles resident blocks/CU (2 -> 3-4) to hide the
// db/K/V latency (register prefetch kn/vn keeps the pipeline; cost is one
// extra barrier per iter). Transposed-S, fixed-point softmax p=e^(v-10),
// cvt_pk P-packing, in-kernel fp32 db loads, mask via __ballot words.
// Grid 512, XCD key = b%8.
// ---------------------------------------------------------------------------
__global__ __launch_bounds__(256, 2) void attn_mfma(
    const short* __restrict__ q, const short* __restrict__ k,
    const short* __restrict__ vt, const float* __restrict__ db,
    const int* __restrict__ mask, short* __restrict__ o) {
    __shared__ short Ks[64 * 72];
    __shared__ short Vs[64 * 72];
    __shared__ short pl[8][16 * 72];
    const int tid = threadIdx.x;
    const int lane = tid & 63, wid = tid >> 6;
    const int c = lane & 15, g = lane >> 4;
    // decode: f = (b&7) + 8*(u4 + 4*(h + 8*(b>>3)))
    const int f = blockIdx.x;
    const int blo = f & 7;
    const int t = f >> 3;
    const int u4 = t & 3;
    const int h = (t >> 2) & 7;
    const int b = (t >> 5) * 8 + blo;
    const int u = u4 * 4 + wid;   // wave-unit 0..15 within (b,h)
    const int q0A = u * 32;       // tile A: q0A..+15, tile B: q0A+16..+31

    const short* kp = k + (((size_t)b * 8 + h) * 512) * 64;
    const short* vp = vt + (((size_t)b * 8 + h) * 64) * 512;
    const short* qpA = q + (((size_t)b * 8 + h) * 512 + q0A) * 64;
    // direct fp32 db: lane (c,g) reads its q-row, col runs {nt*16+g*4..+3}
    const float* dbA = db + ((size_t)b * 512 + q0A + c) * 512 + g * 4;
    const float* dbB = dbA + (size_t)16 * 512;
    const int* mp = mask + b * 512;

    // mask ballots (SGPR-resident): mm[jj] bit l = mask[jj*64 + l]
    unsigned long long mm[8];
#pragma unroll
    for (int jj = 0; jj < 8; ++jj)
        mm[jj] = __ballot(mp[jj * 64 + lane] != 0);

    // staging coords: seg s in [0,512): row = s>>3 (0..63), c8 = s&7
    const int s0 = tid * 2, s1 = tid * 2 + 1;
    const int kr0 = s0 >> 3, kc0 = (s0 & 7) * 8;
    const int kr1 = s1 >> 3, kc1 = (s1 & 7) * 8;

    // Q as B-fragment: B[col=q=c][kdim=d=g*8+e]
    short8 qA0 = *(const short8*)&qpA[c * 64 + g * 8];
    short8 qA1 = *(const short8*)&qpA[c * 64 + 32 + g * 8];
    short8 qB0 = *(const short8*)&qpA[(16 + c) * 64 + g * 8];
    short8 qB1 = *(const short8*)&qpA[(16 + c) * 64 + 32 + g * 8];

    // prologue: stage K/V tile 0; db tile 0 -> bf16 regs
    {
        short8 k0v = *(const short8*)&kp[kr0 * 64 + kc0];
        short8 k1v = *(const short8*)&kp[kr1 * 64 + kc1];
        short8 v0v = *(const short8*)&vp[kr0 * 512 + kc0];
        short8 v1v = *(const short8*)&vp[kr1 * 512 + kc1];
        *(short8*)&Ks[kr0 * 72 + kc0] = k0v;
        *(short8*)&Ks[kr1 * 72 + kc1] = k1v;
        *(short8*)&Vs[kr0 * 72 + kc0] = v0v;
        *(short8*)&Vs[kr1 * 72 + kc1] = v1v;
    }
    short8 dA0, dA1, dB0, dB1;
    {
        f32x4 a0 = *(const f32x4*)&dbA[0],  a1 = *(const f32x4*)&dbA[16];
        f32x4 a2 = *(const f32x4*)&dbA[32], a3 = *(const f32x4*)&dbA[48];
        dA0 = cvt8(a0, a1); dA1 = cvt8(a2, a3);
        f32x4 b0 = *(const f32x4*)&dbB[0],  b1 = *(const f32x4*)&dbB[16];
        f32x4 b2 = *(const f32x4*)&dbB[32], b3 = *(const f32x4*)&dbB[48];
        dB0 = cvt8(b0, b1); dB1 = cvt8(b2, b3);
    }
    __syncthreads();

    const f32x4 Z = {0.f, 0.f, 0.f, 0.f};
    f32x4 oA[4], oB[4];
    float lsA[4], lsB[4];
#pragma unroll
    for (int dt = 0; dt < 4; ++dt) { oA[dt] = Z; oB[dt] = Z; }
#pragma unroll
    for (int nt = 0; nt < 4; ++nt) { lsA[nt] = 0.f; lsB[nt] = 0.f; }

    short* plA = &pl[wid * 2][0];
    short* plB = &pl[wid * 2 + 1][0];

    for (int jidx = 0; jidx < 8; ++jidx) {
        const int j0 = jidx * 64;
        // 0. issue K/V global loads for next tile (held in regs)
        short8 kn0, kn1, vn0, vn1;
        if (jidx < 7) {
            const int jn = j0 + 64;
            kn0 = *(const short8*)&kp[(jn + kr0) * 64 + kc0];
            kn1 = *(const short8*)&kp[(jn + kr1) * 64 + kc1];
            vn0 = *(const short8*)&vp[kr0 * 512 + jn + kc0];
            vn1 = *(const short8*)&vp[kr1 * 512 + jn + kc1];
        }
        // per-lane mask slice for this j-tile (wave-uniform u64 in SGPR)
        const unsigned long long sh = mm[jidx] >> (g * 4);
        // 1. K fragments from LDS, S^T = K Q^T for both tiles
        short8 kf0, kf1;
        f32x4 sA[4], sB[4];
#pragma unroll
        for (int nt = 0; nt < 4; ++nt) {
            kf0 = *(const short8*)&Ks[(nt * 16 + c) * 72 + g * 8];
            kf1 = *(const short8*)&Ks[(nt * 16 + c) * 72 + 32 + g * 8];
            f32x4 zA = Z, zB = Z;
            __builtin_amdgcn_s_setprio(1);
            zA = MFMA16(kf0, qA0, zA);
            zB = MFMA16(kf0, qB0, zB);
            zA = MFMA16(kf1, qA1, zA);
            zB = MFMA16(kf1, qB1, zB);
            __builtin_amdgcn_s_setprio(0);
            sA[nt] = zA;
            sB[nt] = zB;
        }
        // 2. tile A: scale+db+clip+mask, p=e^(v-10), lane-local l, cvt_pk
#pragma unroll
        for (int nt = 0; nt < 4; ++nt) {
            float pp0, pp1, pp2, pp3;
            {
                int idx = nt * 4;
                float d0 = bf2f(idx < 8 ? dA0[idx] : dA1[idx - 8]);
                float d1 = bf2f(idx + 1 < 8 ? dA0[idx + 1] : dA1[idx - 7]);
                float d2 = bf2f(idx + 2 < 8 ? dA0[idx + 2] : dA1[idx - 6]);
                float d3 = bf2f(idx + 3 < 8 ? dA0[idx + 3] : dA1[idx - 5]);
                float v0 = fminf(fmaxf(fmaf(sA[nt][0], 0.125f, d0), -10.f), 10.f);
                float v1 = fminf(fmaxf(fmaf(sA[nt][1], 0.125f, d1), -10.f), 10.f);
                float v2 = fminf(fmaxf(fmaf(sA[nt][2], 0.125f, d2), -10.f), 10.f);
                float v3 = fminf(fmaxf(fmaf(sA[nt][3], 0.125f, d3), -10.f), 10.f);
                v0 = ((sh >> (nt * 16 + 0)) & 1ull) ? v0 : -30.f;
                v1 = ((sh >> (nt * 16 + 1)) & 1ull) ? v1 : -30.f;
                v2 = ((sh >> (nt * 16 + 2)) & 1ull) ? v2 : -30.f;
                v3 = ((sh >> (nt * 16 + 3)) & 1ull) ? v3 : -30.f;
                pp0 = exp2f(fmaf(v0, 1.442695041f, -14.42695041f));
                pp1 = exp2f(fmaf(v1, 1.442695041f, -14.42695041f));
                pp2 = exp2f(fmaf(v2, 1.442695041f, -14.42695041f));
                pp3 = exp2f(fmaf(v3, 1.442695041f, -14.42695041f));
            }
            lsA[nt] += (pp0 + pp1) + (pp2 + pp3);
            cvtpk_store4(&plA[c * 72 + nt * 16 + g * 4], pp0, pp1, pp2, pp3);
        }
        // 3. prefetch next db A (fp32 -> bf16 immediately, transients only)
        if (jidx < 7) {
            const float* pA = dbA + (jidx + 1) * 64;
            f32x4 a0 = *(const f32x4*)&pA[0],  a1 = *(const f32x4*)&pA[16];
            f32x4 a2 = *(const f32x4*)&pA[32], a3 = *(const f32x4*)&pA[48];
            dA0 = cvt8(a0, a1); dA1 = cvt8(a2, a3);
        }
        // 4. tile B: same
#pragma unroll
        for (int nt = 0; nt < 4; ++nt) {
            float pp0, pp1, pp2, pp3;
            {
                int idx = nt * 4;
                float d0 = bf2f(idx < 8 ? dB0[idx] : dB1[idx - 8]);
                float d1 = bf2f(idx + 1 < 8 ? dB0[idx + 1] : dB1[idx - 7]);
                float d2 = bf2f(idx + 2 < 8 ? dB0[idx + 2] : dB1[idx - 6]);
                float d3 = bf2f(idx + 3 < 8 ? dB0[idx + 3] : dB1[idx - 5]);
                float v0 = fminf(fmaxf(fmaf(sB[nt][0], 0.125f, d0), -10.f), 10.f);
                float v1 = fminf(fmaxf(fmaf(sB[nt][1], 0.125f, d1), -10.f), 10.f);
                float v2 = fminf(fmaxf(fmaf(sB[nt][2], 0.125f, d2), -10.f), 10.f);
                float v3 = fminf(fmaxf(fmaf(sB[nt][3], 0.125f, d3), -10.f), 10.f);
                v0 = ((sh >> (nt * 16 + 0)) & 1ull) ? v0 : -30.f;
                v1 = ((sh >> (nt * 16 + 1)) & 1ull) ? v1 : -30.f;
                v2 = ((sh >> (nt * 16 + 2)) & 1ull) ? v2 : -30.f;
                v3 = ((sh >> (nt * 16 + 3)) & 1ull) ? v3 : -30.f;
                pp0 = exp2f(fmaf(v0, 1.442695041f, -14.42695041f));
                pp1 = exp2f(fmaf(v1, 1.442695041f, -14.42695041f));
                pp2 = exp2f(fmaf(v2, 1.442695041f, -14.42695041f));
                pp3 = exp2f(fmaf(v3, 1.442695041f, -14.42695041f));
            }
            lsB[nt] += (pp0 + pp1) + (pp2 + pp3);
            cvtpk_store4(&plB[c * 72 + nt * 16 + g * 4], pp0, pp1, pp2, pp3);
        }
        // 5. prefetch next db B
        if (jidx < 7) {
            const float* pB = dbB + (jidx + 1) * 64;
            f32x4 b0 = *(const f32x4*)&pB[0],  b1 = *(const f32x4*)&pB[16];
            f32x4 b2 = *(const f32x4*)&pB[32], b3 = *(const f32x4*)&pB[48];
            dB0 = cvt8(b0, b1); dB1 = cvt8(b2, b3);
        }
        // 6. wait LDS (P strips), read P + V fragments, PV MFMA
        asm volatile("s_waitcnt lgkmcnt(0)" ::: "memory");
        __builtin_amdgcn_sched_barrier(0);
        short8 pA0 = *(const short8*)&plA[c * 72 + g * 8];
        short8 pA1 = *(const short8*)&plA[c * 72 + 32 + g * 8];
        short8 pB0 = *(const short8*)&plB[c * 72 + g * 8];
        short8 pB1 = *(const short8*)&plB[c * 72 + 32 + g * 8];
#pragma unroll
        for (int dt = 0; dt < 4; ++dt) {
            short8 vf0 = *(const short8*)&Vs[(dt * 16 + c) * 72 + g * 8];
            short8 vf1 = *(const short8*)&Vs[(dt * 16 + c) * 72 + 32 + g * 8];
            __builtin_amdgcn_s_setprio(1);
            oA[dt] = MFMA16(vf0, pA0, oA[dt]);
            oB[dt] = MFMA16(vf0, pB0, oB[dt]);
            oA[dt] = MFMA16(vf1, pA1, oA[dt]);
            oB[dt] = MFMA16(vf1, pB1, oB[dt]);
            __builtin_amdgcn_s_setprio(0);
        }
        // 7. single-buffer swap: all reads done -> overwrite tile, publish
        if (jidx < 7) {
            __syncthreads();   // everyone finished reading tile j
            *(short8*)&Ks[kr0 * 72 + kc0] = kn0;
            *(short8*)&Ks[kr1 * 72 + kc1] = kn1;
            *(short8*)&Vs[kr0 * 72 + kc0] = vn0;
            *(short8*)&Vs[kr1 * 72 + kc1] = vn1;
            __syncthreads();   // tile j+1 visible
        }
    }
    // epilogue: cross-lane l reduction (once), normalize, packed stores
    float lA = (lsA[0] + lsA[1]) + (lsA[2] + lsA[3]);
    lA += __shfl_xor(lA, 16);
    lA += __shfl_xor(lA, 32);
    float lB = (lsB[0] + lsB[1]) + (lsB[2] + lsB[3]);
    lB += __shfl_xor(lB, 16);
    lB += __shfl_xor(lB, 32);
    const float invA = 1.f / lA, invB = 1.f / lB;
#pragma unroll
    for (int dt = 0; dt < 4; ++dt) {
        short4v wa, wb;
#pragma unroll
        for (int r = 0; r < 4; ++r) {
            wa[r] = f2bf(oA[dt][r] * invA);
            wb[r] = f2bf(oB[dt][r] * invB);
        }
        *(short4v*)&o[((size_t)b * 512 + q0A + c) * 512 + h * 64 + dt * 16 + g * 4] = wa;
        *(short4v*)&o[((size_t)b * 512 + q0A + 16 + c) * 512 + h * 64 + dt * 16 + g * 4] = wb;
    }
}

extern "C" void kernel_launch(void* const* d_in, const int* in_sizes, int n_in,
                              void* d_out, int out_size, void* d_ws, size_t ws_size,
                              hipStream_t stream) {
    const float* x  = (const float*)d_in[0];
    const float* db = (const float*)d_in[1];
    const int* msk  = (const int*)d_in[2];
    const float* wq = (const float*)d_in[3];
    const float* bq = (const float*)d_in[4];
    const float* wk = (const float*)d_in[5];
    const float* bk = (const float*)d_in[6];
    const float* wv = (const float*)d_in[7];
    const float* bv = (const float*)d_in[8];
    const float* wo = (const float*)d_in[9];
    const float* bo = (const float*)d_in[10];
    float* out = (float*)d_out;

    short* qb  = (short*)d_ws;             // [B,H,N,D] bf16
    short* kb  = qb + 4194304;             // [B,H,N,D]
    short* vtb = kb + 4194304;             // [B,H,D,N]
    short* ob  = vtb + 4194304;            // [M,E] bf16 attention output

    qkv128<<<dim3(64, 12), 256, 0, stream>>>(x, wq, wk, wv, bq, bk, bv,
                                             qb, kb, vtb);
    attn_mfma<<<512, 256, 0, stream>>>(qb, kb, vtb, db, msk, ob);
    out128<<<dim3(64, 4), 256, 0, stream>>>(ob, wo, bo, out);
}

// Round 23
// 73.398 us; speedup vs baseline: 1.0482x; 1.0482x over previous
//
#include <hip/hip_runtime.h>

typedef __attribute__((ext_vector_type(8))) short short8;
typedef __attribute__((ext_vector_type(4))) short short4v;
typedef __attribute__((ext_vector_type(4))) float f32x4;

#define MFMA16(A, B, C) __builtin_amdgcn_mfma_f32_16x16x32_bf16(A, B, C, 0, 0, 0)

__device__ __forceinline__ short f2bf(float f) {
    union { float f; unsigned u; } v;
    v.f = f;
    unsigned r = (v.u + 0x7FFFu + ((v.u >> 16) & 1u)) >> 16;
    return (short)r;
}

__device__ __forceinline__ float bf2f(short u) {
    union { unsigned u; float f; } v;
    v.u = ((unsigned)(unsigned short)u) << 16;
    return v.f;
}

// 8x fp32 -> bf16x8 via v_cvt_pk_bf16_f32 (RNE, 1 op per pair).
__device__ __forceinline__ short8 cvt8(f32x4 a, f32x4 b) {
    unsigned u0, u1, u2, u3;
    asm("v_cvt_pk_bf16_f32 %0, %1, %2" : "=v"(u0) : "v"(a[0]), "v"(a[1]));
    asm("v_cvt_pk_bf16_f32 %0, %1, %2" : "=v"(u1) : "v"(a[2]), "v"(a[3]));
    asm("v_cvt_pk_bf16_f32 %0, %1, %2" : "=v"(u2) : "v"(b[0]), "v"(b[1]));
    asm("v_cvt_pk_bf16_f32 %0, %1, %2" : "=v"(u3) : "v"(b[2]), "v"(b[3]));
    union { unsigned u[4]; short8 s; } r;
    r.u[0] = u0; r.u[1] = u1; r.u[2] = u2; r.u[3] = u3;
    return r.s;
}

// 4x fp32 -> bf16x4 packed 8B store (for P strips).
__device__ __forceinline__ void cvtpk_store4(short* dst, float p0, float p1,
                                             float p2, float p3) {
    unsigned w01, w23;
    asm("v_cvt_pk_bf16_f32 %0, %1, %2" : "=v"(w01) : "v"(p0), "v"(p1));
    asm("v_cvt_pk_bf16_f32 %0, %1, %2" : "=v"(w23) : "v"(p2), "v"(p3));
    union { unsigned u[2]; short4v s; } r;
    r.u[0] = w01; r.u[1] = w23;
    *(short4v*)dst = r.s;
}

// ---------------------------------------------------------------------------
// Fused QKV GEMM (r21-proven), 128x128 tile, BK=64, reg-staged dbuf. Both
// panels fp32, converted to bf16 AT WRITE TIME (loads stay outstanding under
// MFMA). Grid (64, 12); z = e0>>9 block-uniform: 0->q, 1->k, 2->v^T.
// ---------------------------------------------------------------------------
__global__ __launch_bounds__(256) void qkv128(
    const float* __restrict__ X, const float* __restrict__ wq,
    const float* __restrict__ wk, const float* __restrict__ wv,
    const float* __restrict__ bq, const float* __restrict__ bk,
    const float* __restrict__ bv, short* __restrict__ qo,
    short* __restrict__ ko, short* __restrict__ vto) {
    __shared__ short As[128 * 72];
    __shared__ short Bs[128 * 72];
    const int tid = threadIdx.x, lane = tid & 63, wid = tid >> 6;
    const int c = lane & 15, g = lane >> 4;
    const int wr = (wid >> 1) * 64, wc = (wid & 1) * 64;
    const int m0 = blockIdx.x * 128, e0 = blockIdx.y * 128;
    const int z = e0 >> 9;
    const float* Wf = (z == 0) ? wq : (z == 1) ? wk : wv;  // block-uniform
    const int er0 = e0 & 511;

    const f32x4 Z = {0.f, 0.f, 0.f, 0.f};
    f32x4 acc[4][4];
#pragma unroll
    for (int i = 0; i < 4; ++i)
#pragma unroll
        for (int j = 0; j < 4; ++j) acc[i][j] = Z;

    // fp32 staging registers (converted at write time)
    f32x4 pa0[4], pa1[4], pb0[4], pb1[4];
#pragma unroll
    for (int p = 0; p < 4; ++p) {
        int u = p * 256 + tid;
        int row = u >> 3, c8 = u & 7;
        const float* xs = &X[(size_t)(m0 + row) * 512 + c8 * 8];
        const float* ws = &Wf[(size_t)(er0 + row) * 512 + c8 * 8];
        pa0[p] = *(const f32x4*)xs;  pa1[p] = *(const f32x4*)(xs + 4);
        pb0[p] = *(const f32x4*)ws;  pb1[p] = *(const f32x4*)(ws + 4);
    }
    for (int it = 0; it < 8; ++it) {
        __syncthreads();
#pragma unroll
        for (int p = 0; p < 4; ++p) {
            int u = p * 256 + tid;
            int row = u >> 3, c8 = u & 7;
            *(short8*)&As[row * 72 + c8 * 8] = cvt8(pa0[p], pa1[p]);
            *(short8*)&Bs[row * 72 + c8 * 8] = cvt8(pb0[p], pb1[p]);
        }
        if (it < 7) {
            int k0 = (it + 1) * 64;
#pragma unroll
            for (int p = 0; p < 4; ++p) {
                int u = p * 256 + tid;
                int row = u >> 3, c8 = u & 7;
                const float* xs = &X[(size_t)(m0 + row) * 512 + k0 + c8 * 8];
                const float* ws = &Wf[(size_t)(er0 + row) * 512 + k0 + c8 * 8];
                pa0[p] = *(const f32x4*)xs;  pa1[p] = *(const f32x4*)(xs + 4);
                pb0[p] = *(const f32x4*)ws;  pb1[p] = *(const f32x4*)(ws + 4);
            }
        }
        __syncthreads();
#pragma unroll
        for (int ks = 0; ks < 2; ++ks) {
            short8 af[4], bf[4];
#pragma unroll
            for (int mt = 0; mt < 4; ++mt)
                af[mt] = *(const short8*)&As[(wr + mt * 16 + c) * 72 + ks * 32 + g * 8];
#pragma unroll
            for (int nt = 0; nt < 4; ++nt)
                bf[nt] = *(const short8*)&Bs[(wc + nt * 16 + c) * 72 + ks * 32 + g * 8];
#pragma unroll
            for (int mt = 0; mt < 4; ++mt)
#pragma unroll
                for (int nt = 0; nt < 4; ++nt)
                    acc[mt][nt] = MFMA16(af[mt], bf[nt], acc[mt][nt]);
        }
    }

    // epilogue: route by z (block-uniform)
    const float* bp = (z == 0) ? bq : (z == 1) ? bk : bv;
    if (z < 2) {
        short* out = (z == 0) ? qo : ko;
#pragma unroll
        for (int nt = 0; nt < 4; ++nt) {
            int eh = er0 + wc + nt * 16 + c;
            float bsv = bp[eh];
            int h = eh >> 6, d = eh & 63;
#pragma unroll
            for (int mt = 0; mt < 4; ++mt)
#pragma unroll
                for (int r = 0; r < 4; ++r) {
                    int m = m0 + wr + mt * 16 + g * 4 + r;
                    int bb = m >> 9, n = m & 511;
                    out[(((size_t)bb * 8 + h) * 512 + n) * 64 + d] =
                        f2bf(acc[mt][nt][r] + bsv);
                }
        }
    } else {
#pragma unroll
        for (int nt = 0; nt < 4; ++nt) {
            int eh = er0 + wc + nt * 16 + c;
            float bsv = bp[eh];
            int h = eh >> 6, d = eh & 63;
#pragma unroll
            for (int mt = 0; mt < 4; ++mt) {
                int m = m0 + wr + mt * 16 + g * 4;
                int bb = m >> 9, n = m & 511;  // 4 consecutive n
                short4v w;
#pragma unroll
                for (int r = 0; r < 4; ++r) w[r] = f2bf(acc[mt][nt][r] + bsv);
                *(short4v*)&vto[(((size_t)bb * 8 + h) * 64 + d) * 512 + n] = w;
            }
        }
    }
}

// ---------------------------------------------------------------------------
// Output projection (r21-proven), 128x128 tile, reg-staged; wo fp32 held in
// registers, converted at write time. Grid (64, 4).
// ---------------------------------------------------------------------------
__global__ __launch_bounds__(256) void out128(const short* __restrict__ A,
                                              const float* __restrict__ Wf,
                                              const float* __restrict__ bo,
                                              float* __restrict__ out) {
    __shared__ short As[128 * 72];
    __shared__ short Bs[128 * 72];
    const int tid = threadIdx.x, lane = tid & 63, wid = tid >> 6;
    const int c = lane & 15, g = lane >> 4;
    const int wr = (wid >> 1) * 64, wc = (wid & 1) * 64;
    const int m0 = blockIdx.x * 128, e0 = blockIdx.y * 128;

    const f32x4 Z = {0.f, 0.f, 0.f, 0.f};
    f32x4 acc[4][4];
#pragma unroll
    for (int i = 0; i < 4; ++i)
#pragma unroll
        for (int j = 0; j < 4; ++j) acc[i][j] = Z;

    short8 pa[4];
    f32x4 pb0[4], pb1[4];
#pragma unroll
    for (int p = 0; p < 4; ++p) {
        int u = p * 256 + tid;
        int row = u >> 3, c8 = u & 7;
        pa[p] = *(const short8*)&A[(size_t)(m0 + row) * 512 + c8 * 8];
        const float* ws = &Wf[(size_t)(e0 + row) * 512 + c8 * 8];
        pb0[p] = *(const f32x4*)ws;  pb1[p] = *(const f32x4*)(ws + 4);
    }
    for (int it = 0; it < 8; ++it) {
        __syncthreads();
#pragma unroll
        for (int p = 0; p < 4; ++p) {
            int u = p * 256 + tid;
            int row = u >> 3, c8 = u & 7;
            *(short8*)&As[row * 72 + c8 * 8] = pa[p];
            *(short8*)&Bs[row * 72 + c8 * 8] = cvt8(pb0[p], pb1[p]);
        }
        if (it < 7) {
            int k0 = (it + 1) * 64;
#pragma unroll
            for (int p = 0; p < 4; ++p) {
                int u = p * 256 + tid;
                int row = u >> 3, c8 = u & 7;
                pa[p] = *(const short8*)&A[(size_t)(m0 + row) * 512 + k0 + c8 * 8];
                const float* ws = &Wf[(size_t)(e0 + row) * 512 + k0 + c8 * 8];
                pb0[p] = *(const f32x4*)ws;  pb1[p] = *(const f32x4*)(ws + 4);
            }
        }
        __syncthreads();
#pragma unroll
        for (int ks = 0; ks < 2; ++ks) {
            short8 af[4], bf[4];
#pragma unroll
            for (int mt = 0; mt < 4; ++mt)
                af[mt] = *(const short8*)&As[(wr + mt * 16 + c) * 72 + ks * 32 + g * 8];
#pragma unroll
            for (int nt = 0; nt < 4; ++nt)
                bf[nt] = *(const short8*)&Bs[(wc + nt * 16 + c) * 72 + ks * 32 + g * 8];
#pragma unroll
            for (int mt = 0; mt < 4; ++mt)
#pragma unroll
                for (int nt = 0; nt < 4; ++nt)
                    acc[mt][nt] = MFMA16(af[mt], bf[nt], acc[mt][nt]);
        }
    }

#pragma unroll
    for (int nt = 0; nt < 4; ++nt) {
        int e = e0 + wc + nt * 16 + c;
        float bsv = bo[e];
#pragma unroll
        for (int mt = 0; mt < 4; ++mt)
#pragma unroll
            for (int r = 0; r < 4; ++r) {
                int m = m0 + wr + mt * 16 + g * 4 + r;
                out[(size_t)m * 512 + e] = acc[mt][nt][r] + bsv;
            }
    }
}

// ---------------------------------------------------------------------------
// MFMA flash attention (r19/r21-proven, best measured): block-shared
// DOUBLE-BUFFERED K/V LDS staging, transposed-S, fixed-point softmax
// p=e^(v-10), cvt_pk P-packing, in-kernel fp32 db loads (cvt_pk to bf16
// immediately; L2-resident under b%8 XCD key), mask via 8 prologue
// __ballot words (masked -> -30). Grid 512, XCD key = b%8.
// r22 single-buffer variant regressed (extra barrier > occupancy gain;
// VGPR-capped at ~3 waves/SIMD regardless of LDS).
// ---------------------------------------------------------------------------
__global__ __launch_bounds__(256, 2) void attn_mfma(
    const short* __restrict__ q, const short* __restrict__ k,
    const short* __restrict__ vt, const float* __restrict__ db,
    const int* __restrict__ mask, short* __restrict__ o) {
    __shared__ short Ks[2][64 * 72];
    __shared__ short Vs[2][64 * 72];
    __shared__ short pl[8][16 * 72];
    const int tid = threadIdx.x;
    const int lane = tid & 63, wid = tid >> 6;
    const int c = lane & 15, g = lane >> 4;
    // decode: f = (b&7) + 8*(u4 + 4*(h + 8*(b>>3)))
    const int f = blockIdx.x;
    const int blo = f & 7;
    const int t = f >> 3;
    const int u4 = t & 3;
    const int h = (t >> 2) & 7;
    const int b = (t >> 5) * 8 + blo;
    const int u = u4 * 4 + wid;   // wave-unit 0..15 within (b,h)
    const int q0A = u * 32;       // tile A: q0A..+15, tile B: q0A+16..+31

    const short* kp = k + (((size_t)b * 8 + h) * 512) * 64;
    const short* vp = vt + (((size_t)b * 8 + h) * 64) * 512;
    const short* qpA = q + (((size_t)b * 8 + h) * 512 + q0A) * 64;
    // direct fp32 db: lane (c,g) reads its q-row, col runs {nt*16+g*4..+3}
    const float* dbA = db + ((size_t)b * 512 + q0A + c) * 512 + g * 4;
    const float* dbB = dbA + (size_t)16 * 512;
    const int* mp = mask + b * 512;

    // mask ballots (SGPR-resident): mm[jj] bit l = mask[jj*64 + l]
    unsigned long long mm[8];
#pragma unroll
    for (int jj = 0; jj < 8; ++jj)
        mm[jj] = __ballot(mp[jj * 64 + lane] != 0);

    // staging coords: seg s in [0,512): row = s>>3 (0..63), c8 = s&7
    const int s0 = tid * 2, s1 = tid * 2 + 1;
    const int kr0 = s0 >> 3, kc0 = (s0 & 7) * 8;
    const int kr1 = s1 >> 3, kc1 = (s1 & 7) * 8;

    // Q as B-fragment: B[col=q=c][kdim=d=g*8+e]
    short8 qA0 = *(const short8*)&qpA[c * 64 + g * 8];
    short8 qA1 = *(const short8*)&qpA[c * 64 + 32 + g * 8];
    short8 qB0 = *(const short8*)&qpA[(16 + c) * 64 + g * 8];
    short8 qB1 = *(const short8*)&qpA[(16 + c) * 64 + 32 + g * 8];

    // prologue: stage K/V tile 0 into buffer 0; db tile 0 -> bf16 regs
    {
        short8 k0v = *(const short8*)&kp[kr0 * 64 + kc0];
        short8 k1v = *(const short8*)&kp[kr1 * 64 + kc1];
        short8 v0v = *(const short8*)&vp[kr0 * 512 + kc0];
        short8 v1v = *(const short8*)&vp[kr1 * 512 + kc1];
        *(short8*)&Ks[0][kr0 * 72 + kc0] = k0v;
        *(short8*)&Ks[0][kr1 * 72 + kc1] = k1v;
        *(short8*)&Vs[0][kr0 * 72 + kc0] = v0v;
        *(short8*)&Vs[0][kr1 * 72 + kc1] = v1v;
    }
    short8 dA0, dA1, dB0, dB1;
    {
        f32x4 a0 = *(const f32x4*)&dbA[0],  a1 = *(const f32x4*)&dbA[16];
        f32x4 a2 = *(const f32x4*)&dbA[32], a3 = *(const f32x4*)&dbA[48];
        dA0 = cvt8(a0, a1); dA1 = cvt8(a2, a3);
        f32x4 b0 = *(const f32x4*)&dbB[0],  b1 = *(const f32x4*)&dbB[16];
        f32x4 b2 = *(const f32x4*)&dbB[32], b3 = *(const f32x4*)&dbB[48];
        dB0 = cvt8(b0, b1); dB1 = cvt8(b2, b3);
    }
    __syncthreads();

    const f32x4 Z = {0.f, 0.f, 0.f, 0.f};
    f32x4 oA[4], oB[4];
    float lsA[4], lsB[4];
#pragma unroll
    for (int dt = 0; dt < 4; ++dt) { oA[dt] = Z; oB[dt] = Z; }
#pragma unroll
    for (int nt = 0; nt < 4; ++nt) { lsA[nt] = 0.f; lsB[nt] = 0.f; }

    short* plA = &pl[wid * 2][0];
    short* plB = &pl[wid * 2 + 1][0];

    for (int jidx = 0; jidx < 8; ++jidx) {
        const int cur = jidx & 1;
        const int j0 = jidx * 64;
        // 0. issue K/V global loads for next tile
        short8 kn0, kn1, vn0, vn1;
        if (jidx < 7) {
            const int jn = j0 + 64;
            kn0 = *(const short8*)&kp[(jn + kr0) * 64 + kc0];
            kn1 = *(const short8*)&kp[(jn + kr1) * 64 + kc1];
            vn0 = *(const short8*)&vp[kr0 * 512 + jn + kc0];
            vn1 = *(const short8*)&vp[kr1 * 512 + jn + kc1];
        }
        // per-lane mask slice for this j-tile (wave-uniform u64 in SGPR)
        const unsigned long long sh = mm[jidx] >> (g * 4);
        // 1. K fragments from LDS, S^T = K Q^T for both tiles
        short8 kf0, kf1;
        f32x4 sA[4], sB[4];
#pragma unroll
        for (int nt = 0; nt < 4; ++nt) {
            kf0 = *(const short8*)&Ks[cur][(nt * 16 + c) * 72 + g * 8];
            kf1 = *(const short8*)&Ks[cur][(nt * 16 + c) * 72 + 32 + g * 8];
            f32x4 zA = Z, zB = Z;
            __builtin_amdgcn_s_setprio(1);
            zA = MFMA16(kf0, qA0, zA);
            zB = MFMA16(kf0, qB0, zB);
            zA = MFMA16(kf1, qA1, zA);
            zB = MFMA16(kf1, qB1, zB);
            __builtin_amdgcn_s_setprio(0);
            sA[nt] = zA;
            sB[nt] = zB;
        }
        // 2. tile A: scale+db+clip+mask, p=e^(v-10), lane-local l, cvt_pk
#pragma unroll
        for (int nt = 0; nt < 4; ++nt) {
            float pp0, pp1, pp2, pp3;
            {
                int idx = nt * 4;
                float d0 = bf2f(idx < 8 ? dA0[idx] : dA1[idx - 8]);
                float d1 = bf2f(idx + 1 < 8 ? dA0[idx + 1] : dA1[idx - 7]);
                float d2 = bf2f(idx + 2 < 8 ? dA0[idx + 2] : dA1[idx - 6]);
                float d3 = bf2f(idx + 3 < 8 ? dA0[idx + 3] : dA1[idx - 5]);
                float v0 = fminf(fmaxf(fmaf(sA[nt][0], 0.125f, d0), -10.f), 10.f);
                float v1 = fminf(fmaxf(fmaf(sA[nt][1], 0.125f, d1), -10.f), 10.f);
                float v2 = fminf(fmaxf(fmaf(sA[nt][2], 0.125f, d2), -10.f), 10.f);
                float v3 = fminf(fmaxf(fmaf(sA[nt][3], 0.125f, d3), -10.f), 10.f);
                v0 = ((sh >> (nt * 16 + 0)) & 1ull) ? v0 : -30.f;
                v1 = ((sh >> (nt * 16 + 1)) & 1ull) ? v1 : -30.f;
                v2 = ((sh >> (nt * 16 + 2)) & 1ull) ? v2 : -30.f;
                v3 = ((sh >> (nt * 16 + 3)) & 1ull) ? v3 : -30.f;
                pp0 = exp2f(fmaf(v0, 1.442695041f, -14.42695041f));
                pp1 = exp2f(fmaf(v1, 1.442695041f, -14.42695041f));
                pp2 = exp2f(fmaf(v2, 1.442695041f, -14.42695041f));
                pp3 = exp2f(fmaf(v3, 1.442695041f, -14.42695041f));
            }
            lsA[nt] += (pp0 + pp1) + (pp2 + pp3);
            cvtpk_store4(&plA[c * 72 + nt * 16 + g * 4], pp0, pp1, pp2, pp3);
        }
        // 3. prefetch next db A (fp32 -> bf16 immediately, transients only)
        if (jidx < 7) {
            const float* pA = dbA + (jidx + 1) * 64;
            f32x4 a0 = *(const f32x4*)&pA[0],  a1 = *(const f32x4*)&pA[16];
            f32x4 a2 = *(const f32x4*)&pA[32], a3 = *(const f32x4*)&pA[48];
            dA0 = cvt8(a0, a1); dA1 = cvt8(a2, a3);
        }
        // 4. tile B: same
#pragma unroll
        for (int nt = 0; nt < 4; ++nt) {
            float pp0, pp1, pp2, pp3;
            {
                int idx = nt * 4;
                float d0 = bf2f(idx < 8 ? dB0[idx] : dB1[idx - 8]);
                float d1 = bf2f(idx + 1 < 8 ? dB0[idx + 1] : dB1[idx - 7]);
                float d2 = bf2f(idx + 2 < 8 ? dB0[idx + 2] : dB1[idx - 6]);
                float d3 = bf2f(idx + 3 < 8 ? dB0[idx + 3] : dB1[idx - 5]);
                float v0 = fminf(fmaxf(fmaf(sB[nt][0], 0.125f, d0), -10.f), 10.f);
                float v1 = fminf(fmaxf(fmaf(sB[nt][1], 0.125f, d1), -10.f), 10.f);
                float v2 = fminf(fmaxf(fmaf(sB[nt][2], 0.125f, d2), -10.f), 10.f);
                float v3 = fminf(fmaxf(fmaf(sB[nt][3], 0.125f, d3), -10.f), 10.f);
                v0 = ((sh >> (nt * 16 + 0)) & 1ull) ? v0 : -30.f;
                v1 = ((sh >> (nt * 16 + 1)) & 1ull) ? v1 : -30.f;
                v2 = ((sh >> (nt * 16 + 2)) & 1ull) ? v2 : -30.f;
                v3 = ((sh >> (nt * 16 + 3)) & 1ull) ? v3 : -30.f;
                pp0 = exp2f(fmaf(v0, 1.442695041f, -14.42695041f));
                pp1 = exp2f(fmaf(v1, 1.442695041f, -14.42695041f));
                pp2 = exp2f(fmaf(v2, 1.442695041f, -14.42695041f));
                pp3 = exp2f(fmaf(v3, 1.442695041f, -14.42695041f));
            }
            lsB[nt] += (pp0 + pp1) + (pp2 + pp3);
            cvtpk_store4(&plB[c * 72 + nt * 16 + g * 4], pp0, pp1, pp2, pp3);
        }
        // 5. prefetch next db B
        if (jidx < 7) {
            const float* pB = dbB + (jidx + 1) * 64;
            f32x4 b0 = *(const f32x4*)&pB[0],  b1 = *(const f32x4*)&pB[16];
            f32x4 b2 = *(const f32x4*)&pB[32], b3 = *(const f32x4*)&pB[48];
            dB0 = cvt8(b0, b1); dB1 = cvt8(b2, b3);
        }
        // 6. wait LDS (P strips), read P + V fragments, PV MFMA
        asm volatile("s_waitcnt lgkmcnt(0)" ::: "memory");
        __builtin_amdgcn_sched_barrier(0);
        short8 pA0 = *(const short8*)&plA[c * 72 + g * 8];
        short8 pA1 = *(const short8*)&plA[c * 72 + 32 + g * 8];
        short8 pB0 = *(const short8*)&plB[c * 72 + g * 8];
        short8 pB1 = *(const short8*)&plB[c * 72 + 32 + g * 8];
#pragma unroll
        for (int dt = 0; dt < 4; ++dt) {
            short8 vf0 = *(const short8*)&Vs[cur][(dt * 16 + c) * 72 + g * 8];
            short8 vf1 = *(const short8*)&Vs[cur][(dt * 16 + c) * 72 + 32 + g * 8];
            __builtin_amdgcn_s_setprio(1);
            oA[dt] = MFMA16(vf0, pA0, oA[dt]);
            oB[dt] = MFMA16(vf0, pB0, oB[dt]);
            oA[dt] = MFMA16(vf1, pA1, oA[dt]);
            oB[dt] = MFMA16(vf1, pB1, oB[dt]);
            __builtin_amdgcn_s_setprio(0);
        }
        // 7. write next K/V tile into the other buffer; barrier for next iter
        if (jidx < 7) {
            const int nxt = cur ^ 1;
            *(short8*)&Ks[nxt][kr0 * 72 + kc0] = kn0;
            *(short8*)&Ks[nxt][kr1 * 72 + kc1] = kn1;
            *(short8*)&Vs[nxt][kr0 * 72 + kc0] = vn0;
            *(short8*)&Vs[nxt][kr1 * 72 + kc1] = vn1;
            __syncthreads();
        }
    }
    // epilogue: cross-lane l reduction (once), normalize, packed stores
    float lA = (lsA[0] + lsA[1]) + (lsA[2] + lsA[3]);
    lA += __shfl_xor(lA, 16);
    lA += __shfl_xor(lA, 32);
    float lB = (lsB[0] + lsB[1]) + (lsB[2] + lsB[3]);
    lB += __shfl_xor(lB, 16);
    lB += __shfl_xor(lB, 32);
    const float invA = 1.f / lA, invB = 1.f / lB;
#pragma unroll
    for (int dt = 0; dt < 4; ++dt) {
        short4v wa, wb;
#pragma unroll
        for (int r = 0; r < 4; ++r) {
            wa[r] = f2bf(oA[dt][r] * invA);
            wb[r] = f2bf(oB[dt][r] * invB);
        }
        *(short4v*)&o[((size_t)b * 512 + q0A + c) * 512 + h * 64 + dt * 16 + g * 4] = wa;
        *(short4v*)&o[((size_t)b * 512 + q0A + 16 + c) * 512 + h * 64 + dt * 16 + g * 4] = wb;
    }
}

extern "C" void kernel_launch(void* const* d_in, const int* in_sizes, int n_in,
                              void* d_out, int out_size, void* d_ws, size_t ws_size,
                              hipStream_t stream) {
    const float* x  = (const float*)d_in[0];
    const float* db = (const float*)d_in[1];
    const int* msk  = (const int*)d_in[2];
    const float* wq = (const float*)d_in[3];
    const float* bq = (const float*)d_in[4];
    const float* wk = (const float*)d_in[5];
    const float* bk = (const float*)d_in[6];
    const float* wv = (const float*)d_in[7];
    const float* bv = (const float*)d_in[8];
    const float* wo = (const float*)d_in[9];
    const float* bo = (const float*)d_in[10];
    float* out = (float*)d_out;

    short* qb  = (short*)d_ws;             // [B,H,N,D] bf16
    short* kb  = qb + 4194304;             // [B,H,N,D]
    short* vtb = kb + 4194304;             // [B,H,D,N]
    short* ob  = vtb + 4194304;            // [M,E] bf16 attention output

    qkv128<<<dim3(64, 12), 256, 0, stream>>>(x, wq, wk, wv, bq, bk, bv,
                                             qb, kb, vtb);
    attn_mfma<<<512, 256, 0, stream>>>(qb, kb, vtb, db, msk, ob);
    out128<<<dim3(64, 4), 256, 0, stream>>>(ob, wo, bo, out);
}

// Round 24
// 72.706 us; speedup vs baseline: 1.0582x; 1.0095x over previous
//
#include <hip/hip_runtime.h>

typedef __attribute__((ext_vector_type(8))) short short8;
typedef __attribute__((ext_vector_type(4))) short short4v;
typedef __attribute__((ext_vector_type(4))) float f32x4;

#define MFMA16(A, B, C) __builtin_amdgcn_mfma_f32_16x16x32_bf16(A, B, C, 0, 0, 0)

__device__ __forceinline__ short f2bf(float f) {
    union { float f; unsigned u; } v;
    v.f = f;
    unsigned r = (v.u + 0x7FFFu + ((v.u >> 16) & 1u)) >> 16;
    return (short)r;
}

__device__ __forceinline__ float bf2f(short u) {
    union { unsigned u; float f; } v;
    v.u = ((unsigned)(unsigned short)u) << 16;
    return v.f;
}

// 8x fp32 -> bf16x8 via v_cvt_pk_bf16_f32 (RNE, 1 op per pair).
__device__ __forceinline__ short8 cvt8(f32x4 a, f32x4 b) {
    unsigned u0, u1, u2, u3;
    asm("v_cvt_pk_bf16_f32 %0, %1, %2" : "=v"(u0) : "v"(a[0]), "v"(a[1]));
    asm("v_cvt_pk_bf16_f32 %0, %1, %2" : "=v"(u1) : "v"(a[2]), "v"(a[3]));
    asm("v_cvt_pk_bf16_f32 %0, %1, %2" : "=v"(u2) : "v"(b[0]), "v"(b[1]));
    asm("v_cvt_pk_bf16_f32 %0, %1, %2" : "=v"(u3) : "v"(b[2]), "v"(b[3]));
    union { unsigned u[4]; short8 s; } r;
    r.u[0] = u0; r.u[1] = u1; r.u[2] = u2; r.u[3] = u3;
    return r.s;
}

// 4x fp32 -> bf16x4 packed 8B store (for P strips).
__device__ __forceinline__ void cvtpk_store4(short* dst, float p0, float p1,
                                             float p2, float p3) {
    unsigned w01, w23;
    asm("v_cvt_pk_bf16_f32 %0, %1, %2" : "=v"(w01) : "v"(p0), "v"(p1));
    asm("v_cvt_pk_bf16_f32 %0, %1, %2" : "=v"(w23) : "v"(p2), "v"(p3));
    union { unsigned u[2]; short4v s; } r;
    r.u[0] = w01; r.u[1] = w23;
    *(short4v*)dst = r.s;
}

// Q is pre-scaled by 0.125*log2(e) at projection time so attention scores
// arrive directly in the log2 domain (see attn softmax).
#define QSCALE 0.18033688011112042f   // 0.125 * log2(e)
#define L2E    1.4426950408889634f
#define CLMP   14.426950408889634f    // 10 * log2(e)

// ---------------------------------------------------------------------------
// Fused QKV GEMM (r21-proven), 128x128 tile, BK=64, reg-staged dbuf. Both
// panels fp32, converted to bf16 AT WRITE TIME (loads stay outstanding under
// MFMA). Q-epilogue bakes QSCALE into q. Grid (64, 12); z = e0>>9
// block-uniform: 0->q, 1->k, 2->v^T.
// ---------------------------------------------------------------------------
__global__ __launch_bounds__(256) void qkv128(
    const float* __restrict__ X, const float* __restrict__ wq,
    const float* __restrict__ wk, const float* __restrict__ wv,
    const float* __restrict__ bq, const float* __restrict__ bk,
    const float* __restrict__ bv, short* __restrict__ qo,
    short* __restrict__ ko, short* __restrict__ vto) {
    __shared__ short As[128 * 72];
    __shared__ short Bs[128 * 72];
    const int tid = threadIdx.x, lane = tid & 63, wid = tid >> 6;
    const int c = lane & 15, g = lane >> 4;
    const int wr = (wid >> 1) * 64, wc = (wid & 1) * 64;
    const int m0 = blockIdx.x * 128, e0 = blockIdx.y * 128;
    const int z = e0 >> 9;
    const float* Wf = (z == 0) ? wq : (z == 1) ? wk : wv;  // block-uniform
    const int er0 = e0 & 511;

    const f32x4 Z = {0.f, 0.f, 0.f, 0.f};
    f32x4 acc[4][4];
#pragma unroll
    for (int i = 0; i < 4; ++i)
#pragma unroll
        for (int j = 0; j < 4; ++j) acc[i][j] = Z;

    // fp32 staging registers (converted at write time)
    f32x4 pa0[4], pa1[4], pb0[4], pb1[4];
#pragma unroll
    for (int p = 0; p < 4; ++p) {
        int u = p * 256 + tid;
        int row = u >> 3, c8 = u & 7;
        const float* xs = &X[(size_t)(m0 + row) * 512 + c8 * 8];
        const float* ws = &Wf[(size_t)(er0 + row) * 512 + c8 * 8];
        pa0[p] = *(const f32x4*)xs;  pa1[p] = *(const f32x4*)(xs + 4);
        pb0[p] = *(const f32x4*)ws;  pb1[p] = *(const f32x4*)(ws + 4);
    }
    for (int it = 0; it < 8; ++it) {
        __syncthreads();
#pragma unroll
        for (int p = 0; p < 4; ++p) {
            int u = p * 256 + tid;
            int row = u >> 3, c8 = u & 7;
            *(short8*)&As[row * 72 + c8 * 8] = cvt8(pa0[p], pa1[p]);
            *(short8*)&Bs[row * 72 + c8 * 8] = cvt8(pb0[p], pb1[p]);
        }
        if (it < 7) {
            int k0 = (it + 1) * 64;
#pragma unroll
            for (int p = 0; p < 4; ++p) {
                int u = p * 256 + tid;
                int row = u >> 3, c8 = u & 7;
                const float* xs = &X[(size_t)(m0 + row) * 512 + k0 + c8 * 8];
                const float* ws = &Wf[(size_t)(er0 + row) * 512 + k0 + c8 * 8];
                pa0[p] = *(const f32x4*)xs;  pa1[p] = *(const f32x4*)(xs + 4);
                pb0[p] = *(const f32x4*)ws;  pb1[p] = *(const f32x4*)(ws + 4);
            }
        }
        __syncthreads();
#pragma unroll
        for (int ks = 0; ks < 2; ++ks) {
            short8 af[4], bf[4];
#pragma unroll
            for (int mt = 0; mt < 4; ++mt)
                af[mt] = *(const short8*)&As[(wr + mt * 16 + c) * 72 + ks * 32 + g * 8];
#pragma unroll
            for (int nt = 0; nt < 4; ++nt)
                bf[nt] = *(const short8*)&Bs[(wc + nt * 16 + c) * 72 + ks * 32 + g * 8];
#pragma unroll
            for (int mt = 0; mt < 4; ++mt)
#pragma unroll
                for (int nt = 0; nt < 4; ++nt)
                    acc[mt][nt] = MFMA16(af[mt], bf[nt], acc[mt][nt]);
        }
    }

    // epilogue: route by z (block-uniform); Q pre-scaled by QSCALE
    const float* bp = (z == 0) ? bq : (z == 1) ? bk : bv;
    if (z < 2) {
        short* out = (z == 0) ? qo : ko;
        const float sc = (z == 0) ? QSCALE : 1.0f;
#pragma unroll
        for (int nt = 0; nt < 4; ++nt) {
            int eh = er0 + wc + nt * 16 + c;
            float bsv = bp[eh];
            int h = eh >> 6, d = eh & 63;
#pragma unroll
            for (int mt = 0; mt < 4; ++mt)
#pragma unroll
                for (int r = 0; r < 4; ++r) {
                    int m = m0 + wr + mt * 16 + g * 4 + r;
                    int bb = m >> 9, n = m & 511;
                    out[(((size_t)bb * 8 + h) * 512 + n) * 64 + d] =
                        f2bf((acc[mt][nt][r] + bsv) * sc);
                }
        }
    } else {
#pragma unroll
        for (int nt = 0; nt < 4; ++nt) {
            int eh = er0 + wc + nt * 16 + c;
            float bsv = bp[eh];
            int h = eh >> 6, d = eh & 63;
#pragma unroll
            for (int mt = 0; mt < 4; ++mt) {
                int m = m0 + wr + mt * 16 + g * 4;
                int bb = m >> 9, n = m & 511;  // 4 consecutive n
                short4v w;
#pragma unroll
                for (int r = 0; r < 4; ++r) w[r] = f2bf(acc[mt][nt][r] + bsv);
                *(short4v*)&vto[(((size_t)bb * 8 + h) * 64 + d) * 512 + n] = w;
            }
        }
    }
}

// ---------------------------------------------------------------------------
// Output projection (r21-proven), 128x128 tile, reg-staged; wo fp32 held in
// registers, converted at write time. Grid (64, 4).
// ---------------------------------------------------------------------------
__global__ __launch_bounds__(256) void out128(const short* __restrict__ A,
                                              const float* __restrict__ Wf,
                                              const float* __restrict__ bo,
                                              float* __restrict__ out) {
    __shared__ short As[128 * 72];
    __shared__ short Bs[128 * 72];
    const int tid = threadIdx.x, lane = tid & 63, wid = tid >> 6;
    const int c = lane & 15, g = lane >> 4;
    const int wr = (wid >> 1) * 64, wc = (wid & 1) * 64;
    const int m0 = blockIdx.x * 128, e0 = blockIdx.y * 128;

    const f32x4 Z = {0.f, 0.f, 0.f, 0.f};
    f32x4 acc[4][4];
#pragma unroll
    for (int i = 0; i < 4; ++i)
#pragma unroll
        for (int j = 0; j < 4; ++j) acc[i][j] = Z;

    short8 pa[4];
    f32x4 pb0[4], pb1[4];
#pragma unroll
    for (int p = 0; p < 4; ++p) {
        int u = p * 256 + tid;
        int row = u >> 3, c8 = u & 7;
        pa[p] = *(const short8*)&A[(size_t)(m0 + row) * 512 + c8 * 8];
        const float* ws = &Wf[(size_t)(e0 + row) * 512 + c8 * 8];
        pb0[p] = *(const f32x4*)ws;  pb1[p] = *(const f32x4*)(ws + 4);
    }
    for (int it = 0; it < 8; ++it) {
        __syncthreads();
#pragma unroll
        for (int p = 0; p < 4; ++p) {
            int u = p * 256 + tid;
            int row = u >> 3, c8 = u & 7;
            *(short8*)&As[row * 72 + c8 * 8] = pa[p];
            *(short8*)&Bs[row * 72 + c8 * 8] = cvt8(pb0[p], pb1[p]);
        }
        if (it < 7) {
            int k0 = (it + 1) * 64;
#pragma unroll
            for (int p = 0; p < 4; ++p) {
                int u = p * 256 + tid;
                int row = u >> 3, c8 = u & 7;
                pa[p] = *(const short8*)&A[(size_t)(m0 + row) * 512 + k0 + c8 * 8];
                const float* ws = &Wf[(size_t)(e0 + row) * 512 + k0 + c8 * 8];
                pb0[p] = *(const f32x4*)ws;  pb1[p] = *(const f32x4*)(ws + 4);
            }
        }
        __syncthreads();
#pragma unroll
        for (int ks = 0; ks < 2; ++ks) {
            short8 af[4], bf[4];
#pragma unroll
            for (int mt = 0; mt < 4; ++mt)
                af[mt] = *(const short8*)&As[(wr + mt * 16 + c) * 72 + ks * 32 + g * 8];
#pragma unroll
            for (int nt = 0; nt < 4; ++nt)
                bf[nt] = *(const short8*)&Bs[(wc + nt * 16 + c) * 72 + ks * 32 + g * 8];
#pragma unroll
            for (int mt = 0; mt < 4; ++mt)
#pragma unroll
                for (int nt = 0; nt < 4; ++nt)
                    acc[mt][nt] = MFMA16(af[mt], bf[nt], acc[mt][nt]);
        }
    }

#pragma unroll
    for (int nt = 0; nt < 4; ++nt) {
        int e = e0 + wc + nt * 16 + c;
        float bsv = bo[e];
#pragma unroll
        for (int mt = 0; mt < 4; ++mt)
#pragma unroll
            for (int r = 0; r < 4; ++r) {
                int m = m0 + wr + mt * 16 + g * 4 + r;
                out[(size_t)m * 512 + e] = acc[mt][nt][r] + bsv;
            }
    }
}

// ---------------------------------------------------------------------------
// MFMA flash attention (r23 core + log2-domain softmax): Q pre-scaled by
// 0.125*log2e, so v2 = fma(db, log2e, s) is the score in log2 domain;
// p = exp2(clamp(v2, +-14.427)) directly — softmax is scale-invariant so the
// exponent bias is dropped (P <= 2^14.4, fine in bf16/fp32; masked -> -50,
// all-masked rows still uniform). One fewer VALU op + shorter dep chain per
// score. Block-shared double-buffered K/V staging, cvt_pk P-pack, fp32 db
// loads, __ballot mask. Grid 512, XCD key = b%8.
// ---------------------------------------------------------------------------
__global__ __launch_bounds__(256, 2) void attn_mfma(
    const short* __restrict__ q, const short* __restrict__ k,
    const short* __restrict__ vt, const float* __restrict__ db,
    const int* __restrict__ mask, short* __restrict__ o) {
    __shared__ short Ks[2][64 * 72];
    __shared__ short Vs[2][64 * 72];
    __shared__ short pl[8][16 * 72];
    const int tid = threadIdx.x;
    const int lane = tid & 63, wid = tid >> 6;
    const int c = lane & 15, g = lane >> 4;
    // decode: f = (b&7) + 8*(u4 + 4*(h + 8*(b>>3)))
    const int f = blockIdx.x;
    const int blo = f & 7;
    const int t = f >> 3;
    const int u4 = t & 3;
    const int h = (t >> 2) & 7;
    const int b = (t >> 5) * 8 + blo;
    const int u = u4 * 4 + wid;   // wave-unit 0..15 within (b,h)
    const int q0A = u * 32;       // tile A: q0A..+15, tile B: q0A+16..+31

    const short* kp = k + (((size_t)b * 8 + h) * 512) * 64;
    const short* vp = vt + (((size_t)b * 8 + h) * 64) * 512;
    const short* qpA = q + (((size_t)b * 8 + h) * 512 + q0A) * 64;
    // direct fp32 db: lane (c,g) reads its q-row, col runs {nt*16+g*4..+3}
    const float* dbA = db + ((size_t)b * 512 + q0A + c) * 512 + g * 4;
    const float* dbB = dbA + (size_t)16 * 512;
    const int* mp = mask + b * 512;

    // mask ballots (SGPR-resident): mm[jj] bit l = mask[jj*64 + l]
    unsigned long long mm[8];
#pragma unroll
    for (int jj = 0; jj < 8; ++jj)
        mm[jj] = __ballot(mp[jj * 64 + lane] != 0);

    // staging coords: seg s in [0,512): row = s>>3 (0..63), c8 = s&7
    const int s0 = tid * 2, s1 = tid * 2 + 1;
    const int kr0 = s0 >> 3, kc0 = (s0 & 7) * 8;
    const int kr1 = s1 >> 3, kc1 = (s1 & 7) * 8;

    // Q as B-fragment: B[col=q=c][kdim=d=g*8+e]
    short8 qA0 = *(const short8*)&qpA[c * 64 + g * 8];
    short8 qA1 = *(const short8*)&qpA[c * 64 + 32 + g * 8];
    short8 qB0 = *(const short8*)&qpA[(16 + c) * 64 + g * 8];
    short8 qB1 = *(const short8*)&qpA[(16 + c) * 64 + 32 + g * 8];

    // prologue: stage K/V tile 0 into buffer 0; db tile 0 -> bf16 regs
    {
        short8 k0v = *(const short8*)&kp[kr0 * 64 + kc0];
        short8 k1v = *(const short8*)&kp[kr1 * 64 + kc1];
        short8 v0v = *(const short8*)&vp[kr0 * 512 + kc0];
        short8 v1v = *(const short8*)&vp[kr1 * 512 + kc1];
        *(short8*)&Ks[0][kr0 * 72 + kc0] = k0v;
        *(short8*)&Ks[0][kr1 * 72 + kc1] = k1v;
        *(short8*)&Vs[0][kr0 * 72 + kc0] = v0v;
        *(short8*)&Vs[0][kr1 * 72 + kc1] = v1v;
    }
    short8 dA0, dA1, dB0, dB1;
    {
        f32x4 a0 = *(const f32x4*)&dbA[0],  a1 = *(const f32x4*)&dbA[16];
        f32x4 a2 = *(const f32x4*)&dbA[32], a3 = *(const f32x4*)&dbA[48];
        dA0 = cvt8(a0, a1); dA1 = cvt8(a2, a3);
        f32x4 b0 = *(const f32x4*)&dbB[0],  b1 = *(const f32x4*)&dbB[16];
        f32x4 b2 = *(const f32x4*)&dbB[32], b3 = *(const f32x4*)&dbB[48];
        dB0 = cvt8(b0, b1); dB1 = cvt8(b2, b3);
    }
    __syncthreads();

    const f32x4 Z = {0.f, 0.f, 0.f, 0.f};
    f32x4 oA[4], oB[4];
    float lsA[4], lsB[4];
#pragma unroll
    for (int dt = 0; dt < 4; ++dt) { oA[dt] = Z; oB[dt] = Z; }
#pragma unroll
    for (int nt = 0; nt < 4; ++nt) { lsA[nt] = 0.f; lsB[nt] = 0.f; }

    short* plA = &pl[wid * 2][0];
    short* plB = &pl[wid * 2 + 1][0];

    for (int jidx = 0; jidx < 8; ++jidx) {
        const int cur = jidx & 1;
        const int j0 = jidx * 64;
        // 0. issue K/V global loads for next tile
        short8 kn0, kn1, vn0, vn1;
        if (jidx < 7) {
            const int jn = j0 + 64;
            kn0 = *(const short8*)&kp[(jn + kr0) * 64 + kc0];
            kn1 = *(const short8*)&kp[(jn + kr1) * 64 + kc1];
            vn0 = *(const short8*)&vp[kr0 * 512 + jn + kc0];
            vn1 = *(const short8*)&vp[kr1 * 512 + jn + kc1];
        }
        // per-lane mask slice for this j-tile (wave-uniform u64 in SGPR)
        const unsigned long long sh = mm[jidx] >> (g * 4);
        // 1. K fragments from LDS, S^T = K Q^T for both tiles
        short8 kf0, kf1;
        f32x4 sA[4], sB[4];
#pragma unroll
        for (int nt = 0; nt < 4; ++nt) {
            kf0 = *(const short8*)&Ks[cur][(nt * 16 + c) * 72 + g * 8];
            kf1 = *(const short8*)&Ks[cur][(nt * 16 + c) * 72 + 32 + g * 8];
            f32x4 zA = Z, zB = Z;
            __builtin_amdgcn_s_setprio(1);
            zA = MFMA16(kf0, qA0, zA);
            zB = MFMA16(kf0, qB0, zB);
            zA = MFMA16(kf1, qA1, zA);
            zB = MFMA16(kf1, qB1, zB);
            __builtin_amdgcn_s_setprio(0);
            sA[nt] = zA;
            sB[nt] = zB;
        }
        // 2. tile A: v2 = fma(db, log2e, s); clamp; mask; p = exp2(v2)
#pragma unroll
        for (int nt = 0; nt < 4; ++nt) {
            float pp0, pp1, pp2, pp3;
            {
                int idx = nt * 4;
                float d0 = bf2f(idx < 8 ? dA0[idx] : dA1[idx - 8]);
                float d1 = bf2f(idx + 1 < 8 ? dA0[idx + 1] : dA1[idx - 7]);
                float d2 = bf2f(idx + 2 < 8 ? dA0[idx + 2] : dA1[idx - 6]);
                float d3 = bf2f(idx + 3 < 8 ? dA0[idx + 3] : dA1[idx - 5]);
                float v0 = fminf(fmaxf(fmaf(d0, L2E, sA[nt][0]), -CLMP), CLMP);
                float v1 = fminf(fmaxf(fmaf(d1, L2E, sA[nt][1]), -CLMP), CLMP);
                float v2 = fminf(fmaxf(fmaf(d2, L2E, sA[nt][2]), -CLMP), CLMP);
                float v3 = fminf(fmaxf(fmaf(d3, L2E, sA[nt][3]), -CLMP), CLMP);
                v0 = ((sh >> (nt * 16 + 0)) & 1ull) ? v0 : -50.f;
                v1 = ((sh >> (nt * 16 + 1)) & 1ull) ? v1 : -50.f;
                v2 = ((sh >> (nt * 16 + 2)) & 1ull) ? v2 : -50.f;
                v3 = ((sh >> (nt * 16 + 3)) & 1ull) ? v3 : -50.f;
                pp0 = exp2f(v0);
                pp1 = exp2f(v1);
                pp2 = exp2f(v2);
                pp3 = exp2f(v3);
            }
            lsA[nt] += (pp0 + pp1) + (pp2 + pp3);
            cvtpk_store4(&plA[c * 72 + nt * 16 + g * 4], pp0, pp1, pp2, pp3);
        }
        // 3. prefetch next db A (fp32 -> bf16 immediately, transients only)
        if (jidx < 7) {
            const float* pA = dbA + (jidx + 1) * 64;
            f32x4 a0 = *(const f32x4*)&pA[0],  a1 = *(const f32x4*)&pA[16];
            f32x4 a2 = *(const f32x4*)&pA[32], a3 = *(const f32x4*)&pA[48];
            dA0 = cvt8(a0, a1); dA1 = cvt8(a2, a3);
        }
        // 4. tile B: same
#pragma unroll
        for (int nt = 0; nt < 4; ++nt) {
            float pp0, pp1, pp2, pp3;
            {
                int idx = nt * 4;
                float d0 = bf2f(idx < 8 ? dB0[idx] : dB1[idx - 8]);
                float d1 = bf2f(idx + 1 < 8 ? dB0[idx + 1] : dB1[idx - 7]);
                float d2 = bf2f(idx + 2 < 8 ? dB0[idx + 2] : dB1[idx - 6]);
                float d3 = bf2f(idx + 3 < 8 ? dB0[idx + 3] : dB1[idx - 5]);
                float v0 = fminf(fmaxf(fmaf(d0, L2E, sB[nt][0]), -CLMP), CLMP);
                float v1 = fminf(fmaxf(fmaf(d1, L2E, sB[nt][1]), -CLMP), CLMP);
                float v2 = fminf(fmaxf(fmaf(d2, L2E, sB[nt][2]), -CLMP), CLMP);
                float v3 = fminf(fmaxf(fmaf(d3, L2E, sB[nt][3]), -CLMP), CLMP);
                v0 = ((sh >> (nt * 16 + 0)) & 1ull) ? v0 : -50.f;
                v1 = ((sh >> (nt * 16 + 1)) & 1ull) ? v1 : -50.f;
                v2 = ((sh >> (nt * 16 + 2)) & 1ull) ? v2 : -50.f;
                v3 = ((sh >> (nt * 16 + 3)) & 1ull) ? v3 : -50.f;
                pp0 = exp2f(v0);
                pp1 = exp2f(v1);
                pp2 = exp2f(v2);
                pp3 = exp2f(v3);
            }
            lsB[nt] += (pp0 + pp1) + (pp2 + pp3);
            cvtpk_store4(&plB[c * 72 + nt * 16 + g * 4], pp0, pp1, pp2, pp3);
        }
        // 5. prefetch next db B
        if (jidx < 7) {
            const float* pB = dbB + (jidx + 1) * 64;
            f32x4 b0 = *(const f32x4*)&pB[0],  b1 = *(const f32x4*)&pB[16];
            f32x4 b2 = *(const f32x4*)&pB[32], b3 = *(const f32x4*)&pB[48];
            dB0 = cvt8(b0, b1); dB1 = cvt8(b2, b3);
        }
        // 6. wait LDS (P strips), read P + V fragments, PV MFMA
        asm volatile("s_waitcnt lgkmcnt(0)" ::: "memory");
        __builtin_amdgcn_sched_barrier(0);
        short8 pA0 = *(const short8*)&plA[c * 72 + g * 8];
        short8 pA1 = *(const short8*)&plA[c * 72 + 32 + g * 8];
        short8 pB0 = *(const short8*)&plB[c * 72 + g * 8];
        short8 pB1 = *(const short8*)&plB[c * 72 + 32 + g * 8];
#pragma unroll
        for (int dt = 0; dt < 4; ++dt) {
            short8 vf0 = *(const short8*)&Vs[cur][(dt * 16 + c) * 72 + g * 8];
            short8 vf1 = *(const short8*)&Vs[cur][(dt * 16 + c) * 72 + 32 + g * 8];
            __builtin_amdgcn_s_setprio(1);
            oA[dt] = MFMA16(vf0, pA0, oA[dt]);
            oB[dt] = MFMA16(vf0, pB0, oB[dt]);
            oA[dt] = MFMA16(vf1, pA1, oA[dt]);
            oB[dt] = MFMA16(vf1, pB1, oB[dt]);
            __builtin_amdgcn_s_setprio(0);
        }
        // 7. write next K/V tile into the other buffer; barrier for next iter
        if (jidx < 7) {
            const int nxt = cur ^ 1;
            *(short8*)&Ks[nxt][kr0 * 72 + kc0] = kn0;
            *(short8*)&Ks[nxt][kr1 * 72 + kc1] = kn1;
            *(short8*)&Vs[nxt][kr0 * 72 + kc0] = vn0;
            *(short8*)&Vs[nxt][kr1 * 72 + kc1] = vn1;
            __syncthreads();
        }
    }
    // epilogue: cross-lane l reduction (once), normalize, packed stores
    float lA = (lsA[0] + lsA[1]) + (lsA[2] + lsA[3]);
    lA += __shfl_xor(lA, 16);
    lA += __shfl_xor(lA, 32);
    float lB = (lsB[0] + lsB[1]) + (lsB[2] + lsB[3]);
    lB += __shfl_xor(lB, 16);
    lB += __shfl_xor(lB, 32);
    const float invA = 1.f / lA, invB = 1.f / lB;
#pragma unroll
    for (int dt = 0; dt < 4; ++dt) {
        short4v wa, wb;
#pragma unroll
        for (int r = 0; r < 4; ++r) {
            wa[r] = f2bf(oA[dt][r] * invA);
            wb[r] = f2bf(oB[dt][r] * invB);
        }
        *(short4v*)&o[((size_t)b * 512 + q0A + c) * 512 + h * 64 + dt * 16 + g * 4] = wa;
        *(short4v*)&o[((size_t)b * 512 + q0A + 16 + c) * 512 + h * 64 + dt * 16 + g * 4] = wb;
    }
}

extern "C" void kernel_launch(void* const* d_in, const int* in_sizes, int n_in,
                              void* d_out, int out_size, void* d_ws, size_t ws_size,
                              hipStream_t stream) {
    const float* x  = (const float*)d_in[0];
    const float* db = (const float*)d_in[1];
    const int* msk  = (const int*)d_in[2];
    const float* wq = (const float*)d_in[3];
    const float* bq = (const float*)d_in[4];
    const float* wk = (const float*)d_in[5];
    const float* bk = (const float*)d_in[6];
    const float* wv = (const float*)d_in[7];
    const float* bv = (const float*)d_in[8];
    const float* wo = (const float*)d_in[9];
    const float* bo = (const float*)d_in[10];
    float* out = (float*)d_out;

    short* qb  = (short*)d_ws;             // [B,H,N,D] bf16 (pre-scaled)
    short* kb  = qb + 4194304;             // [B,H,N,D]
    short* vtb = kb + 4194304;             // [B,H,D,N]
    short* ob  = vtb + 4194304;            // [M,E] bf16 attention output

    qkv128<<<dim3(64, 12), 256, 0, stream>>>(x, wq, wk, wv, bq, bk, bv,
                                             qb, kb, vtb);
    attn_mfma<<<512, 256, 0, stream>>>(qb, kb, vtb, db, msk, ob);
    out128<<<dim3(64, 4), 256, 0, stream>>>(ob, wo, bo, out);
}